// Round 25
// baseline (155.342 us; speedup 1.0000x reference)
//
#include <hip/hip_runtime.h>
#include <hip/hip_bf16.h>
#include <stdint.h>

#define NB 16
#define JXX 4096
#define JQQ 512
#define DDD 256
#define LOG2E 1.44269504f

typedef __attribute__((ext_vector_type(8))) _Float16 f16x8;
typedef __attribute__((ext_vector_type(4))) _Float16 f16x4;
typedef __attribute__((ext_vector_type(4))) float f32x4;

__device__ __forceinline__ uint16_t f2h(float f) {
    union { _Float16 h; uint16_t s; } u; u.h = (_Float16)f; return u.s;
}
__device__ __forceinline__ float h2f(uint16_t s) {
    union { _Float16 h; uint16_t s; } u; u.s = s; return (float)u.h;
}

__device__ __forceinline__ void gload_lds16(const void* g, void* l) {
    __builtin_amdgcn_global_load_lds(
        (const __attribute__((address_space(1))) void*)g,
        (__attribute__((address_space(3))) void*)l, 16, 0, 0);
}

#define VMW(N) asm volatile("s_waitcnt vmcnt(" #N ")" ::: "memory")

// ---------------- merged prep: [0,256) mask | [256,768) q tiles | [768,816) W3 ----------------
__global__ void k_prep(const void* cmask, const void* qmask,
                       const float* __restrict__ qg,
                       const float* __restrict__ Wr, const float* __restrict__ Wg,
                       uint8_t* cm8, uint8_t* qm8,
                       uint16_t* __restrict__ qS, uint16_t* __restrict__ qTS,
                       uint16_t* __restrict__ WP3) {
    __shared__ __align__(16) char smem[16896];
    const int blk = blockIdx.x;
    const int t = threadIdx.x;

    if (blk < 256) {
        int i = blk * 256 + t;
        uint32_t w0c = *(const uint32_t*)cmask;
        uint32_t w0q = *(const uint32_t*)qmask;
        int mc = (w0c == 1u) ? 1 : (w0c == 0x3f800000u ? 2 : 0);
        int mq = (w0q == 1u) ? 1 : (w0q == 0x3f800000u ? 2 : 0);
        if (i < NB * JXX) {
            uint8_t v;
            if (mc == 1)      v = ((const int*)cmask)[i] != 0;
            else if (mc == 2) v = ((const float*)cmask)[i] != 0.0f;
            else              v = ((const uint8_t*)cmask)[i] != 0;
            cm8[i] = v;
        }
        if (i < NB * JQQ) {
            uint8_t v;
            if (mq == 1)      v = ((const int*)qmask)[i] != 0;
            else if (mq == 2) v = ((const float*)qmask)[i] != 0.0f;
            else              v = ((const uint8_t*)qmask)[i] != 0;
            qm8[i] = v;
        }
    } else if (blk < 768) {
        float (*tile)[65] = (float (*)[65])smem;
        const int idx = blk - 256;
        const int b = idx >> 5, jb = idx & 7, db = (idx & 31) >> 3;
        const int j0 = jb * 64, d0 = db * 64;
        #pragma unroll
        for (int i = 0; i < 16; i++) {
            int e = t + 256 * i;
            int r = e >> 6, c = e & 63;
            tile[r][c] = qg[((long)b * JQQ + j0 + r) * DDD + d0 + c];
        }
        __syncthreads();
        #pragma unroll
        for (int i = 0; i < 2; i++) {
            int e = t + 256 * i;
            int r = e >> 3, c8 = e & 7;
            f16x8 v;
            #pragma unroll
            for (int k = 0; k < 8; k++) v[k] = (_Float16)tile[r][c8 * 8 + k];
            int jt = (j0 >> 5) + (r >> 5);
            int row = r & 31;
            int d8 = (d0 >> 3) + c8;
            int byt = ((row * 512 + d8 * 16) ^ ((row & 7) << 4));
            *(f16x8*)(qS + ((long)(b * 16 + jt)) * 8192 + (byt >> 1)) = v;
        }
        #pragma unroll
        for (int i = 0; i < 2; i++) {
            int e = t + 256 * i;
            int dd = e >> 3, j8 = e & 7;
            f16x8 v;
            #pragma unroll
            for (int k = 0; k < 8; k++) v[k] = (_Float16)tile[j8 * 8 + k][dd];
            int jt = (j0 >> 5) + (j8 >> 2);
            int d = d0 + dd;
            int byt = ((d * 64 + (j8 & 3) * 16) ^ (((d >> 1) & 3) << 4));
            *(f16x8*)(qTS + ((long)(b * 16 + jt)) * 8192 + (byt >> 1)) = v;
        }
    } else {
        _Float16* tile = (_Float16*)smem;
        const int idx = blk - 768;
        const int ktl = idx & 7, rem = idx >> 3;
        const int comp = rem % 3, rg = rem / 3;
        const float* W = rg ? Wg : Wr;
        const int base0 = (comp == 0 ? 0 : comp == 1 ? 256 : 512) + ktl * 32;
        #pragma unroll
        for (int i = 0; i < 32; i++) {
            int e = t + 256 * i;
            int r = e >> 8, ccol = e & 255;
            float v = W[(long)(base0 + r) * 256 + ccol];
            if (comp == 0)      v += W[(long)(768 + ktl * 32 + r) * 256 + ccol];
            else if (comp == 1) v -= W[(long)(768 + ktl * 32 + r) * 256 + ccol];
            tile[r * 264 + ccol] = (_Float16)v;
        }
        __syncthreads();
        const int step = ktl * 3 + comp;
        #pragma unroll
        for (int ss = 0; ss < 4; ss++) {
            int slot = ss * 256 + t;
            int ntg = slot >> 6, lane = slot & 63;
            int gg = lane >> 4, l = lane & 15;
            f16x8 v;
            #pragma unroll
            for (int i = 0; i < 8; i++) v[i] = tile[(gg * 8 + i) * 264 + ntg * 16 + l];
            int hh = ntg >> 3, ntl = ntg & 7;
            long off = (long)step * 16384 + hh * 8192 + rg * 4096 + ntl * 512 + lane * 8;
            *(f16x8*)(WP3 + off) = v;
        }
    }
}

// ---------------- fused attention v8: 16 rows/wave, 1024 blocks, single-buffered ----------------
// grid (JX/64, B), 256 thr, 4 waves x 16 x-rows. LDS ~37.5KB -> 3-4 blocks/CU
// (was grid-limited at 2). Same v7 barrier/vmcnt skeleton.
__global__ __launch_bounds__(256, 2) void k_attn(
    const float* __restrict__ cg,
    const uint16_t* __restrict__ qS,
    const uint16_t* __restrict__ qTS,
    const uint8_t* __restrict__ cm8,
    const uint8_t* __restrict__ qm8,
    uint16_t* __restrict__ qa16,
    uint16_t* __restrict__ c16)
{
    __shared__ __align__(16) uint16_t qbuf[8192];
    __shared__ __align__(16) uint16_t qTbuf[8192];
    __shared__ __align__(16) uint16_t P_lds[4 * 16 * 40];
    __shared__ __align__(16) uint32_t qm_lds[128];

    const int b = blockIdx.y;
    const int t = threadIdx.x;
    const int wave = t >> 6;
    const int lane = t & 63;
    const int l15 = lane & 15;
    const int g = lane >> 4;
    const int xw = blockIdx.x * 64 + wave * 16;

    if (t < 128) {
        uint32_t m = ((const uint32_t*)(qm8 + (long)b * JQQ))[t];
        qm_lds[t] = m;
    }

    // c fragments (B operand of logits), resident; emit c16 for k_sfu
    f16x8 cfrag[8];
    const long rowg = (long)b * JXX + xw + l15;
    {
        const float* crow = cg + rowg * DDD;
        uint16_t* c16row = c16 + rowg * DDD;
        #pragma unroll
        for (int kb = 0; kb < 8; kb++) {
            float4 v0 = *(const float4*)(crow + kb * 32 + g * 8);
            float4 v1 = *(const float4*)(crow + kb * 32 + g * 8 + 4);
            f16x8 f;
            f[0] = (_Float16)v0.x; f[1] = (_Float16)v0.y; f[2] = (_Float16)v0.z; f[3] = (_Float16)v0.w;
            f[4] = (_Float16)v1.x; f[5] = (_Float16)v1.y; f[6] = (_Float16)v1.z; f[7] = (_Float16)v1.w;
            cfrag[kb] = f;
            *(f16x8*)(c16row + kb * 32 + g * 8) = f;
        }
    }
    const bool cvalid = cm8[rowg] != 0;
    float m_run = cvalid ? -1e30f : 0.0f;
    float s_run = 0.0f;
    const f32x4 fzero = {0.f, 0.f, 0.f, 0.f};
    f32x4 qa[16];
    #pragma unroll
    for (int i = 0; i < 16; i++) qa[i] = fzero;

    const uint16_t* qSb  = qS  + (long)(b * 16) * 8192;
    const uint16_t* qTSb = qTS + (long)(b * 16) * 8192;

    const int kbit = (l15 >> 2) & 1;
    const int qbase = l15 * 256 + (((g * 16) ^ ((l15 & 3) << 4)) >> 1);
    const int qTbase = l15 * 32 + ((g ^ ((l15 >> 1) & 3)) * 8);

    #define STAGE_QS(tile)                                                      \
        { const uint16_t* s1 = qSb + (long)(tile) * 8192;                       \
          _Pragma("unroll")                                                     \
          for (int i = 0; i < 4; i++)                                           \
              gload_lds16(s1 + i * 2048 + t * 8, &qbuf[i * 2048 + wave * 512]); }
    #define STAGE_QT(tile)                                                      \
        { const uint16_t* s2 = qTSb + (long)(tile) * 8192;                      \
          _Pragma("unroll")                                                     \
          for (int i = 0; i < 4; i++)                                           \
              gload_lds16(s2 + i * 2048 + t * 8, &qTbuf[i * 2048 + wave * 512]); }

    STAGE_QS(0);
    STAGE_QT(0);
    VMW(8);                               // qS(0) retired; qT(0) still flying
    __builtin_amdgcn_s_barrier();
    __builtin_amdgcn_sched_barrier(0);

    for (int jt = 0; jt < 16; jt++) {
        uint32_t qmw[2];
        qmw[0] = qm_lds[jt * 8 + g];
        qmw[1] = qm_lds[jt * 8 + 4 + g];

        // ---- logits: D[j][x], x = l15 (reads qbuf) ----
        f32x4 acc[2];
        acc[0] = fzero; acc[1] = fzero;
        __builtin_amdgcn_s_setprio(1);
        #pragma unroll
        for (int js = 0; js < 2; js++) {
            #pragma unroll
            for (int kb = 0; kb < 8; kb++) {
                f16x8 qf = *(const f16x8*)(&qbuf[js * 4096 + qbase + ((kb ^ kbit) << 5)]);
                acc[js] = __builtin_amdgcn_mfma_f32_16x16x32_f16(qf, cfrag[kb], acc[js], 0, 0, 0);
            }
        }
        __builtin_amdgcn_s_setprio(0);
        __builtin_amdgcn_sched_barrier(0);
        __builtin_amdgcn_s_barrier();           // B1: all waves done reading qbuf
        __builtin_amdgcn_sched_barrier(0);
        if (jt < 15) STAGE_QS(jt + 1);          // overwrite qbuf (race-free after B1)

        // ---- online softmax (state per x = l15) ----
        f16x4 pv[2];
        float lmax = -1e30f;
        #pragma unroll
        for (int js = 0; js < 2; js++) {
            #pragma unroll
            for (int r = 0; r < 4; r++) {
                bool qv = (qmw[js] >> (8 * r)) & 0xffu;
                lmax = fmaxf(lmax, qv ? acc[js][r] : -1e30f);
            }
        }
        lmax = fmaxf(lmax, __shfl_xor(lmax, 16));
        lmax = fmaxf(lmax, __shfl_xor(lmax, 32));
        // defer-max (T13, branch-free)
        float m_new = cvalid ? ((lmax > m_run + 8.0f) ? lmax : m_run) : 0.0f;
        float fsc = exp2f((m_run - m_new) * LOG2E);
        float psum = 0.0f;
        #pragma unroll
        for (int js = 0; js < 2; js++) {
            #pragma unroll
            for (int r = 0; r < 4; r++) {
                bool qv = (qmw[js] >> (8 * r)) & 0xffu;
                float p = qv ? exp2f((acc[js][r] - m_new) * LOG2E) : 0.0f;
                if (!cvalid) p = 1.0f;   // c-invalid row: uniform over ALL j
                psum += p;
                pv[js][r] = (_Float16)p;
            }
        }
        s_run = s_run * fsc + psum;
        m_run = m_new;
        if (!__all(fsc == 1.0f)) {
            #pragma unroll
            for (int dt = 0; dt < 16; dt++) {
                qa[dt][0] *= fsc; qa[dt][1] *= fsc;
                qa[dt][2] *= fsc; qa[dt][3] *= fsc;
            }
        }

        uint16_t* Pw0 = P_lds + wave * 640;
        *(f16x4*)(Pw0 + l15 * 40 + g * 4) = pv[0];
        *(f16x4*)(Pw0 + l15 * 40 + 16 + g * 4) = pv[1];
        f16x8 pa = *(const f16x8*)(Pw0 + l15 * 40 + g * 8);

        // retire qT(jt): queue = [qT(jt) 8 (oldest), qS(jt+1) 8]
        if (jt < 15) { VMW(8); } else { VMW(0); }
        __builtin_amdgcn_s_barrier();           // B2: qT(jt) visible to all waves
        __builtin_amdgcn_sched_barrier(0);

        // ---- PV (reads qTbuf) ----
        __builtin_amdgcn_s_setprio(1);
        #pragma unroll
        for (int dt = 0; dt < 16; dt++) {
            f16x8 bq = *(const f16x8*)(&qTbuf[qTbase + dt * 512]);
            qa[dt] = __builtin_amdgcn_mfma_f32_16x16x32_f16(bq, pa, qa[dt], 0, 0, 0);
        }
        __builtin_amdgcn_s_setprio(0);
        __builtin_amdgcn_sched_barrier(0);
        __builtin_amdgcn_s_barrier();           // B3: all waves done reading qTbuf
        __builtin_amdgcn_sched_barrier(0);
        if (jt < 15) {
            STAGE_QT(jt + 1);                   // overwrite qTbuf (race-free after B3)
            VMW(8);                             // retire qS(jt+1) for next logits
        }
        __builtin_amdgcn_s_barrier();           // B0: qS(jt+1) visible to all waves
        __builtin_amdgcn_sched_barrier(0);
    }
    #undef STAGE_QS
    #undef STAGE_QT

    // ---- finalize: divide by per-x sum, store fp16 q_a ----
    float s_tot = s_run + __shfl_xor(s_run, 16);
    s_tot = s_tot + __shfl_xor(s_tot, 32);
    float inv = 1.0f / s_tot;
    uint16_t* outp = qa16 + rowg * DDD;
    #pragma unroll
    for (int dt = 0; dt < 16; dt++) {
        f16x4 v;
        v[0] = (_Float16)(qa[dt][0] * inv);
        v[1] = (_Float16)(qa[dt][1] * inv);
        v[2] = (_Float16)(qa[dt][2] * inv);
        v[3] = (_Float16)(qa[dt][3] * inv);
        *(f16x4*)(outp + dt * 16 + g * 4) = v;
    }
}

// ---------------- fused SFU v13b (unchanged, passing) ----------------
__global__ __launch_bounds__(256, 2) void k_sfu(
    const uint16_t* __restrict__ c16g,
    const uint16_t* __restrict__ qa16,
    const uint16_t* __restrict__ WP3,
    const float* __restrict__ Brb,
    const float* __restrict__ Bgb,
    float* __restrict__ outg)
{
    __shared__ __align__(16) uint16_t ab_lds[2][4096];   // [c/qa][8KB]
    __shared__ __align__(16) uint16_t wbuf[2][16384];    // 2 x 32KB step buffers

    const int t = threadIdx.x;
    const int wave = t >> 6, lane = t & 63;
    const int l15 = lane & 15, g = lane >> 4;
    const long m0 = (long)blockIdx.x * 64;

    const f32x4 fzero = {0.f, 0.f, 0.f, 0.f};
    f32x4 accR[4][4], accG[4][4];   // [mf][nt]
    #pragma unroll
    for (int a = 0; a < 4; a++)
        #pragma unroll
        for (int bq = 0; bq < 4; bq++) { accR[a][bq] = fzero; accG[a][bq] = fzero; }

    const int wrd = (wave >> 1) * 8192 + (wave & 1) * 2048 + lane * 8;

    #define STAGE_CQA(dt_)                                                        \
        { _Pragma("unroll")                                                       \
          for (int j = 0; j < 2; j++) {                                           \
              int pp = j * 256 + t;                                               \
              int row = pp >> 3, pc = pp & 7;                                     \
              long src = (m0 + row) * 256 + (dt_) * 64 + ((pc ^ (row & 7)) << 3); \
              int dst = (j * 256 + wave * 64) * 8;                                \
              gload_lds16(c16g + src, &ab_lds[0][dst]);                           \
              gload_lds16(qa16 + src, &ab_lds[1][dst]);                           \
          } }

    #define STAGE_W(s_)                                                           \
        { _Pragma("unroll")                                                       \
          for (int i = 0; i < 8; i++)                                             \
              gload_lds16(WP3 + (long)(s_) * 16384 + i * 2048 + t * 8,            \
                          &wbuf[(s_) & 1][i * 2048 + wave * 512]); }

    STAGE_CQA(0);
    STAGE_W(0);
    VMW(0);
    __builtin_amdgcn_s_barrier();
    __builtin_amdgcn_sched_barrier(0);

    #pragma unroll
    for (int dt = 0; dt < 4; dt++) {
        #pragma unroll
        for (int kb = 0; kb < 2; kb++) {
            f16x8 cfr[4], qfr[4];
            #pragma unroll
            for (int mf = 0; mf < 4; mf++) {
                int row = mf * 16 + l15;
                int c8 = kb * 4 + g;
                int off = row * 64 + ((c8 ^ (row & 7)) << 3);
                cfr[mf] = *(const f16x8*)(&ab_lds[0][off]);
                qfr[mf] = *(const f16x8*)(&ab_lds[1][off]);
            }
            #pragma unroll
            for (int comp = 0; comp < 3; comp++) {
                const int s = dt * 6 + kb * 3 + comp;
                if (s < 23) STAGE_W(s + 1);
                if (dt < 3 && kb == 1 && comp == 1) STAGE_CQA(dt + 1);
                if (s == 23)                                   { VMW(0); }
                else if (dt < 3 && kb == 1 && comp == 1)       { VMW(12); }
                else                                           { VMW(8); }
                __builtin_amdgcn_s_barrier();
                __builtin_amdgcn_sched_barrier(0);
                f16x8 afc[4];
                #pragma unroll
                for (int mf = 0; mf < 4; mf++) {
                    if (comp == 0)      afc[mf] = cfr[mf];
                    else if (comp == 1) afc[mf] = qfr[mf];
                    else                afc[mf] = cfr[mf] * qfr[mf];
                }
                const uint16_t* Wb = &wbuf[s & 1][wrd];
                __builtin_amdgcn_s_setprio(1);
                #pragma unroll
                for (int nt = 0; nt < 4; nt++) {
                    f16x8 br = *(const f16x8*)(Wb + nt * 512);
                    f16x8 bg = *(const f16x8*)(Wb + 4096 + nt * 512);
                    #pragma unroll
                    for (int mf = 0; mf < 4; mf++) {
                        accR[mf][nt] = __builtin_amdgcn_mfma_f32_16x16x32_f16(afc[mf], br, accR[mf][nt], 0, 0, 0);
                        accG[mf][nt] = __builtin_amdgcn_mfma_f32_16x16x32_f16(afc[mf], bg, accG[mf][nt], 0, 0, 0);
                    }
                }
                __builtin_amdgcn_s_setprio(0);
                __builtin_amdgcn_sched_barrier(0);
                __builtin_amdgcn_s_barrier();
            }
        }
    }
    #undef STAGE_W
    #undef STAGE_CQA

    #pragma unroll
    for (int nt = 0; nt < 4; nt++) {
        int n = wave * 64 + nt * 16 + l15;
        float br = Brb[n], bg = Bgb[n];
        #pragma unroll
        for (int mf = 0; mf < 4; mf++) {
            long rowb = m0 + mf * 16 + g * 4;
            #pragma unroll
            for (int r = 0; r < 4; r++) {
                float pr = accR[mf][nt][r] + br;
                float pg = accG[mf][nt][r] + bg;
                float x = fminf(fmaxf(pr, -30.f), 30.f);
                float e2 = __expf(2.f * x);
                float rr = (e2 - 1.f) / (e2 + 1.f);
                float gv = 1.0f / (1.0f + __expf(-pg));
                float cv = h2f(c16g[(rowb + r) * DDD + n]);
                outg[(rowb + r) * DDD + n] = gv * rr + (1.f - gv) * cv;
            }
        }
    }
}

extern "C" void kernel_launch(void* const* d_in, const int* in_sizes, int n_in,
                              void* d_out, int out_size, void* d_ws, size_t ws_size,
                              hipStream_t stream) {
    const float* c  = (const float*)d_in[0];
    const float* q  = (const float*)d_in[1];
    const float* Wr = (const float*)d_in[2];
    const float* Br = (const float*)d_in[3];
    const float* Wg = (const float*)d_in[4];
    const float* Bg = (const float*)d_in[5];
    const void* cmask = d_in[6];
    const void* qmask = d_in[7];

    char* ws = (char*)d_ws;
    uint16_t* qS    = (uint16_t*)(ws + 0);          //  4,194,304 B
    uint16_t* qTS   = (uint16_t*)(ws + 4194304);    //  4,194,304 B
    uint16_t* qa16  = (uint16_t*)(ws + 8388608);    // 33,554,432 B
    uint16_t* c16   = (uint16_t*)(ws + 41943040);   // 33,554,432 B
    uint16_t* WP3   = (uint16_t*)(ws + 75497472);   //    786,432 B
    uint8_t*  cm8   = (uint8_t*)(ws + 77594624);    //     65,536 B
    uint8_t*  qm8   = (uint8_t*)(ws + 77660160);    //      8,192 B
    (void)in_sizes; (void)n_in; (void)out_size; (void)ws_size;

    k_prep<<<dim3(816), dim3(256), 0, stream>>>(cmask, qmask, q, Wr, Wg,
                                                cm8, qm8, qS, qTS, WP3);
    k_attn<<<dim3(JXX / 64, NB), dim3(256), 0, stream>>>(c, qS, qTS, cm8, qm8, qa16, c16);
    k_sfu<<<dim3((NB * JXX) / 64), dim3(256), 0, stream>>>(
        c16, qa16, WP3, Br, Bg, (float*)d_out);
}

// Round 26
// 149.788 us; speedup vs baseline: 1.0371x; 1.0371x over previous
//
#include <hip/hip_runtime.h>
#include <hip/hip_bf16.h>
#include <stdint.h>

#define NB 16
#define JXX 4096
#define JQQ 512
#define DDD 256
#define LOG2E 1.44269504f

typedef __attribute__((ext_vector_type(8))) _Float16 f16x8;
typedef __attribute__((ext_vector_type(4))) _Float16 f16x4;
typedef __attribute__((ext_vector_type(4))) float f32x4;

__device__ __forceinline__ uint16_t f2h(float f) {
    union { _Float16 h; uint16_t s; } u; u.h = (_Float16)f; return u.s;
}
__device__ __forceinline__ float h2f(uint16_t s) {
    union { _Float16 h; uint16_t s; } u; u.s = s; return (float)u.h;
}

__device__ __forceinline__ void gload_lds16(const void* g, void* l) {
    __builtin_amdgcn_global_load_lds(
        (const __attribute__((address_space(1))) void*)g,
        (__attribute__((address_space(3))) void*)l, 16, 0, 0);
}

#define VMW(N) asm volatile("s_waitcnt vmcnt(" #N ")" ::: "memory")

// ---------------- merged prep: [0,256) mask | [256,768) q tiles | [768,816) W3 ----------------
__global__ void k_prep(const void* cmask, const void* qmask,
                       const float* __restrict__ qg,
                       const float* __restrict__ Wr, const float* __restrict__ Wg,
                       uint8_t* cm8, uint8_t* qm8,
                       uint16_t* __restrict__ qS, uint16_t* __restrict__ qTS,
                       uint16_t* __restrict__ WP3) {
    __shared__ __align__(16) char smem[16896];
    const int blk = blockIdx.x;
    const int t = threadIdx.x;

    if (blk < 256) {
        int i = blk * 256 + t;
        uint32_t w0c = *(const uint32_t*)cmask;
        uint32_t w0q = *(const uint32_t*)qmask;
        int mc = (w0c == 1u) ? 1 : (w0c == 0x3f800000u ? 2 : 0);
        int mq = (w0q == 1u) ? 1 : (w0q == 0x3f800000u ? 2 : 0);
        if (i < NB * JXX) {
            uint8_t v;
            if (mc == 1)      v = ((const int*)cmask)[i] != 0;
            else if (mc == 2) v = ((const float*)cmask)[i] != 0.0f;
            else              v = ((const uint8_t*)cmask)[i] != 0;
            cm8[i] = v;
        }
        if (i < NB * JQQ) {
            uint8_t v;
            if (mq == 1)      v = ((const int*)qmask)[i] != 0;
            else if (mq == 2) v = ((const float*)qmask)[i] != 0.0f;
            else              v = ((const uint8_t*)qmask)[i] != 0;
            qm8[i] = v;
        }
    } else if (blk < 768) {
        float (*tile)[65] = (float (*)[65])smem;
        const int idx = blk - 256;
        const int b = idx >> 5, jb = idx & 7, db = (idx & 31) >> 3;
        const int j0 = jb * 64, d0 = db * 64;
        #pragma unroll
        for (int i = 0; i < 16; i++) {
            int e = t + 256 * i;
            int r = e >> 6, c = e & 63;
            tile[r][c] = qg[((long)b * JQQ + j0 + r) * DDD + d0 + c];
        }
        __syncthreads();
        #pragma unroll
        for (int i = 0; i < 2; i++) {
            int e = t + 256 * i;
            int r = e >> 3, c8 = e & 7;
            f16x8 v;
            #pragma unroll
            for (int k = 0; k < 8; k++) v[k] = (_Float16)tile[r][c8 * 8 + k];
            int jt = (j0 >> 5) + (r >> 5);
            int row = r & 31;
            int d8 = (d0 >> 3) + c8;
            int byt = ((row * 512 + d8 * 16) ^ ((row & 7) << 4));
            *(f16x8*)(qS + ((long)(b * 16 + jt)) * 8192 + (byt >> 1)) = v;
        }
        #pragma unroll
        for (int i = 0; i < 2; i++) {
            int e = t + 256 * i;
            int dd = e >> 3, j8 = e & 7;
            f16x8 v;
            #pragma unroll
            for (int k = 0; k < 8; k++) v[k] = (_Float16)tile[j8 * 8 + k][dd];
            int jt = (j0 >> 5) + (j8 >> 2);
            int d = d0 + dd;
            int byt = ((d * 64 + (j8 & 3) * 16) ^ (((d >> 1) & 3) << 4));
            *(f16x8*)(qTS + ((long)(b * 16 + jt)) * 8192 + (byt >> 1)) = v;
        }
    } else {
        _Float16* tile = (_Float16*)smem;
        const int idx = blk - 768;
        const int ktl = idx & 7, rem = idx >> 3;
        const int comp = rem % 3, rg = rem / 3;
        const float* W = rg ? Wg : Wr;
        const int base0 = (comp == 0 ? 0 : comp == 1 ? 256 : 512) + ktl * 32;
        #pragma unroll
        for (int i = 0; i < 32; i++) {
            int e = t + 256 * i;
            int r = e >> 8, ccol = e & 255;
            float v = W[(long)(base0 + r) * 256 + ccol];
            if (comp == 0)      v += W[(long)(768 + ktl * 32 + r) * 256 + ccol];
            else if (comp == 1) v -= W[(long)(768 + ktl * 32 + r) * 256 + ccol];
            tile[r * 264 + ccol] = (_Float16)v;
        }
        __syncthreads();
        const int step = ktl * 3 + comp;
        #pragma unroll
        for (int ss = 0; ss < 4; ss++) {
            int slot = ss * 256 + t;
            int ntg = slot >> 6, lane = slot & 63;
            int gg = lane >> 4, l = lane & 15;
            f16x8 v;
            #pragma unroll
            for (int i = 0; i < 8; i++) v[i] = tile[(gg * 8 + i) * 264 + ntg * 16 + l];
            int hh = ntg >> 3, ntl = ntg & 7;
            long off = (long)step * 16384 + hh * 8192 + rg * 4096 + ntl * 512 + lane * 8;
            *(f16x8*)(WP3 + off) = v;
        }
    }
}

// ---------------- fused attention v7 (round-24 best): single-buffered, 128 rows/block ----------------
__global__ __launch_bounds__(256, 2) void k_attn(
    const float* __restrict__ cg,
    const uint16_t* __restrict__ qS,
    const uint16_t* __restrict__ qTS,
    const uint8_t* __restrict__ cm8,
    const uint8_t* __restrict__ qm8,
    uint16_t* __restrict__ qa16,
    uint16_t* __restrict__ c16)
{
    __shared__ __align__(16) uint16_t qbuf[8192];
    __shared__ __align__(16) uint16_t qTbuf[8192];
    __shared__ __align__(16) uint16_t P_lds[4 * 32 * 40];
    __shared__ __align__(16) uint32_t qm_lds[128];

    const int b = blockIdx.y;
    const int t = threadIdx.x;
    const int wave = t >> 6;
    const int lane = t & 63;
    const int l15 = lane & 15;
    const int g = lane >> 4;
    const int xw = blockIdx.x * 128 + wave * 32;

    if (t < 128) {
        uint32_t m = ((const uint32_t*)(qm8 + (long)b * JQQ))[t];
        qm_lds[t] = m;
    }

    f16x8 cfrag[2][8];
    bool cvalid[2];
    float m_run[2], s_run[2];
    #pragma unroll
    for (int xs = 0; xs < 2; xs++) {
        const long rowg = (long)b * JXX + xw + xs * 16 + l15;
        const float* crow = cg + rowg * DDD;
        uint16_t* c16row = c16 + rowg * DDD;
        #pragma unroll
        for (int kb = 0; kb < 8; kb++) {
            float4 v0 = *(const float4*)(crow + kb * 32 + g * 8);
            float4 v1 = *(const float4*)(crow + kb * 32 + g * 8 + 4);
            f16x8 f;
            f[0] = (_Float16)v0.x; f[1] = (_Float16)v0.y; f[2] = (_Float16)v0.z; f[3] = (_Float16)v0.w;
            f[4] = (_Float16)v1.x; f[5] = (_Float16)v1.y; f[6] = (_Float16)v1.z; f[7] = (_Float16)v1.w;
            cfrag[xs][kb] = f;
            *(f16x8*)(c16row + kb * 32 + g * 8) = f;
        }
        cvalid[xs] = cm8[rowg] != 0;
        m_run[xs] = cvalid[xs] ? -1e30f : 0.0f;
        s_run[xs] = 0.0f;
    }
    const f32x4 fzero = {0.f, 0.f, 0.f, 0.f};
    f32x4 qa[16][2];
    #pragma unroll
    for (int i = 0; i < 16; i++) { qa[i][0] = fzero; qa[i][1] = fzero; }

    const uint16_t* qSb  = qS  + (long)(b * 16) * 8192;
    const uint16_t* qTSb = qTS + (long)(b * 16) * 8192;

    const int kbit = (l15 >> 2) & 1;
    const int qbase = l15 * 256 + (((g * 16) ^ ((l15 & 3) << 4)) >> 1);
    const int qTbase = l15 * 32 + ((g ^ ((l15 >> 1) & 3)) * 8);

    #define STAGE_QS(tile)                                                      \
        { const uint16_t* s1 = qSb + (long)(tile) * 8192;                       \
          _Pragma("unroll")                                                     \
          for (int i = 0; i < 4; i++)                                           \
              gload_lds16(s1 + i * 2048 + t * 8, &qbuf[i * 2048 + wave * 512]); }
    #define STAGE_QT(tile)                                                      \
        { const uint16_t* s2 = qTSb + (long)(tile) * 8192;                      \
          _Pragma("unroll")                                                     \
          for (int i = 0; i < 4; i++)                                           \
              gload_lds16(s2 + i * 2048 + t * 8, &qTbuf[i * 2048 + wave * 512]); }

    STAGE_QS(0);
    STAGE_QT(0);
    VMW(8);                               // qS(0) retired; qT(0) still flying
    __builtin_amdgcn_s_barrier();
    __builtin_amdgcn_sched_barrier(0);

    for (int jt = 0; jt < 16; jt++) {
        uint32_t qmw[2];
        qmw[0] = qm_lds[jt * 8 + g];
        qmw[1] = qm_lds[jt * 8 + 4 + g];

        // ---- logits (reads qbuf) ----
        f32x4 acc[2][2];
        acc[0][0] = fzero; acc[0][1] = fzero; acc[1][0] = fzero; acc[1][1] = fzero;
        __builtin_amdgcn_s_setprio(1);
        #pragma unroll
        for (int js = 0; js < 2; js++) {
            #pragma unroll
            for (int kb = 0; kb < 8; kb++) {
                f16x8 qf = *(const f16x8*)(&qbuf[js * 4096 + qbase + ((kb ^ kbit) << 5)]);
                acc[js][0] = __builtin_amdgcn_mfma_f32_16x16x32_f16(qf, cfrag[0][kb], acc[js][0], 0, 0, 0);
                acc[js][1] = __builtin_amdgcn_mfma_f32_16x16x32_f16(qf, cfrag[1][kb], acc[js][1], 0, 0, 0);
            }
        }
        __builtin_amdgcn_s_setprio(0);
        __builtin_amdgcn_sched_barrier(0);
        __builtin_amdgcn_s_barrier();           // B1: all waves done reading qbuf
        __builtin_amdgcn_sched_barrier(0);
        if (jt < 15) STAGE_QS(jt + 1);          // overwrite qbuf (race-free after B1)

        // ---- softmax (per xs, state per x = l15) ----
        f16x4 pv[2][2];
        float fsc[2];
        #pragma unroll
        for (int xs = 0; xs < 2; xs++) {
            float lmax = -1e30f;
            #pragma unroll
            for (int js = 0; js < 2; js++) {
                #pragma unroll
                for (int r = 0; r < 4; r++) {
                    bool qv = (qmw[js] >> (8 * r)) & 0xffu;
                    lmax = fmaxf(lmax, qv ? acc[js][xs][r] : -1e30f);
                }
            }
            lmax = fmaxf(lmax, __shfl_xor(lmax, 16));
            lmax = fmaxf(lmax, __shfl_xor(lmax, 32));
            float m_new = cvalid[xs] ? ((lmax > m_run[xs] + 8.0f) ? lmax : m_run[xs]) : 0.0f;
            fsc[xs] = exp2f((m_run[xs] - m_new) * LOG2E);
            float psum = 0.0f;
            #pragma unroll
            for (int js = 0; js < 2; js++) {
                #pragma unroll
                for (int r = 0; r < 4; r++) {
                    bool qv = (qmw[js] >> (8 * r)) & 0xffu;
                    float p = qv ? exp2f((acc[js][xs][r] - m_new) * LOG2E) : 0.0f;
                    if (!cvalid[xs]) p = 1.0f;
                    psum += p;
                    pv[xs][js][r] = (_Float16)p;
                }
            }
            s_run[xs] = s_run[xs] * fsc[xs] + psum;
            m_run[xs] = m_new;
        }
        if (!__all(fsc[0] == 1.0f && fsc[1] == 1.0f)) {
            #pragma unroll
            for (int dt = 0; dt < 16; dt++) {
                #pragma unroll
                for (int xs = 0; xs < 2; xs++) {
                    qa[dt][xs][0] *= fsc[xs]; qa[dt][xs][1] *= fsc[xs];
                    qa[dt][xs][2] *= fsc[xs]; qa[dt][xs][3] *= fsc[xs];
                }
            }
        }

        uint16_t* Pw0 = P_lds + wave * 1280;
        #pragma unroll
        for (int xs = 0; xs < 2; xs++) {
            *(f16x4*)(Pw0 + (xs * 16 + l15) * 40 + g * 4) = pv[xs][0];
            *(f16x4*)(Pw0 + (xs * 16 + l15) * 40 + 16 + g * 4) = pv[xs][1];
        }
        f16x8 pa[2];
        pa[0] = *(const f16x8*)(Pw0 + l15 * 40 + g * 8);
        pa[1] = *(const f16x8*)(Pw0 + (16 + l15) * 40 + g * 8);

        // retire qT(jt): queue = [qT(jt) 8 (oldest), qS(jt+1) 8]
        if (jt < 15) { VMW(8); } else { VMW(0); }
        __builtin_amdgcn_s_barrier();           // B2: qT(jt) visible to all waves
        __builtin_amdgcn_sched_barrier(0);

        // ---- PV (reads qTbuf) ----
        __builtin_amdgcn_s_setprio(1);
        #pragma unroll
        for (int dt = 0; dt < 16; dt++) {
            f16x8 bq = *(const f16x8*)(&qTbuf[qTbase + dt * 512]);
            qa[dt][0] = __builtin_amdgcn_mfma_f32_16x16x32_f16(bq, pa[0], qa[dt][0], 0, 0, 0);
            qa[dt][1] = __builtin_amdgcn_mfma_f32_16x16x32_f16(bq, pa[1], qa[dt][1], 0, 0, 0);
        }
        __builtin_amdgcn_s_setprio(0);
        __builtin_amdgcn_sched_barrier(0);
        __builtin_amdgcn_s_barrier();           // B3: all waves done reading qTbuf
        __builtin_amdgcn_sched_barrier(0);
        if (jt < 15) {
            STAGE_QT(jt + 1);                   // overwrite qTbuf (race-free after B3)
            VMW(8);                             // retire qS(jt+1) for next logits
        }
        __builtin_amdgcn_s_barrier();           // B0: qS(jt+1) visible to all waves
        __builtin_amdgcn_sched_barrier(0);
    }
    #undef STAGE_QS
    #undef STAGE_QT

    #pragma unroll
    for (int xs = 0; xs < 2; xs++) {
        float s_tot = s_run[xs] + __shfl_xor(s_run[xs], 16);
        s_tot = s_tot + __shfl_xor(s_tot, 32);
        float inv = 1.0f / s_tot;
        uint16_t* outp = qa16 + ((long)b * JXX + xw + xs * 16 + l15) * DDD;
        #pragma unroll
        for (int dt = 0; dt < 16; dt++) {
            f16x4 v;
            v[0] = (_Float16)(qa[dt][xs][0] * inv);
            v[1] = (_Float16)(qa[dt][xs][1] * inv);
            v[2] = (_Float16)(qa[dt][xs][2] * inv);
            v[3] = (_Float16)(qa[dt][xs][3] * inv);
            *(f16x4*)(outp + dt * 16 + g * 4) = v;
        }
    }
}

// ---------------- fused SFU v13b (round-24 best): 3-comp folded, 24 steps ----------------
__global__ __launch_bounds__(256, 2) void k_sfu(
    const uint16_t* __restrict__ c16g,
    const uint16_t* __restrict__ qa16,
    const uint16_t* __restrict__ WP3,
    const float* __restrict__ Brb,
    const float* __restrict__ Bgb,
    float* __restrict__ outg)
{
    __shared__ __align__(16) uint16_t ab_lds[2][4096];   // [c/qa][8KB]
    __shared__ __align__(16) uint16_t wbuf[2][16384];    // 2 x 32KB step buffers

    const int t = threadIdx.x;
    const int wave = t >> 6, lane = t & 63;
    const int l15 = lane & 15, g = lane >> 4;
    const long m0 = (long)blockIdx.x * 64;

    const f32x4 fzero = {0.f, 0.f, 0.f, 0.f};
    f32x4 accR[4][4], accG[4][4];   // [mf][nt]
    #pragma unroll
    for (int a = 0; a < 4; a++)
        #pragma unroll
        for (int bq = 0; bq < 4; bq++) { accR[a][bq] = fzero; accG[a][bq] = fzero; }

    const int wrd = (wave >> 1) * 8192 + (wave & 1) * 2048 + lane * 8;

    #define STAGE_CQA(dt_)                                                        \
        { _Pragma("unroll")                                                       \
          for (int j = 0; j < 2; j++) {                                           \
              int pp = j * 256 + t;                                               \
              int row = pp >> 3, pc = pp & 7;                                     \
              long src = (m0 + row) * 256 + (dt_) * 64 + ((pc ^ (row & 7)) << 3); \
              int dst = (j * 256 + wave * 64) * 8;                                \
              gload_lds16(c16g + src, &ab_lds[0][dst]);                           \
              gload_lds16(qa16 + src, &ab_lds[1][dst]);                           \
          } }

    #define STAGE_W(s_)                                                           \
        { _Pragma("unroll")                                                       \
          for (int i = 0; i < 8; i++)                                             \
              gload_lds16(WP3 + (long)(s_) * 16384 + i * 2048 + t * 8,            \
                          &wbuf[(s_) & 1][i * 2048 + wave * 512]); }

    STAGE_CQA(0);
    STAGE_W(0);
    VMW(0);
    __builtin_amdgcn_s_barrier();
    __builtin_amdgcn_sched_barrier(0);

    #pragma unroll
    for (int dt = 0; dt < 4; dt++) {
        #pragma unroll
        for (int kb = 0; kb < 2; kb++) {
            f16x8 cfr[4], qfr[4];
            #pragma unroll
            for (int mf = 0; mf < 4; mf++) {
                int row = mf * 16 + l15;
                int c8 = kb * 4 + g;
                int off = row * 64 + ((c8 ^ (row & 7)) << 3);
                cfr[mf] = *(const f16x8*)(&ab_lds[0][off]);
                qfr[mf] = *(const f16x8*)(&ab_lds[1][off]);
            }
            #pragma unroll
            for (int comp = 0; comp < 3; comp++) {
                const int s = dt * 6 + kb * 3 + comp;
                if (s < 23) STAGE_W(s + 1);
                if (dt < 3 && kb == 1 && comp == 1) STAGE_CQA(dt + 1);
                if (s == 23)                                   { VMW(0); }
                else if (dt < 3 && kb == 1 && comp == 1)       { VMW(12); }
                else                                           { VMW(8); }
                __builtin_amdgcn_s_barrier();
                __builtin_amdgcn_sched_barrier(0);
                f16x8 afc[4];
                #pragma unroll
                for (int mf = 0; mf < 4; mf++) {
                    if (comp == 0)      afc[mf] = cfr[mf];
                    else if (comp == 1) afc[mf] = qfr[mf];
                    else                afc[mf] = cfr[mf] * qfr[mf];
                }
                const uint16_t* Wb = &wbuf[s & 1][wrd];
                __builtin_amdgcn_s_setprio(1);
                #pragma unroll
                for (int nt = 0; nt < 4; nt++) {
                    f16x8 br = *(const f16x8*)(Wb + nt * 512);
                    f16x8 bg = *(const f16x8*)(Wb + 4096 + nt * 512);
                    #pragma unroll
                    for (int mf = 0; mf < 4; mf++) {
                        accR[mf][nt] = __builtin_amdgcn_mfma_f32_16x16x32_f16(afc[mf], br, accR[mf][nt], 0, 0, 0);
                        accG[mf][nt] = __builtin_amdgcn_mfma_f32_16x16x32_f16(afc[mf], bg, accG[mf][nt], 0, 0, 0);
                    }
                }
                __builtin_amdgcn_s_setprio(0);
                __builtin_amdgcn_sched_barrier(0);
                __builtin_amdgcn_s_barrier();
            }
        }
    }
    #undef STAGE_W
    #undef STAGE_CQA

    #pragma unroll
    for (int nt = 0; nt < 4; nt++) {
        int n = wave * 64 + nt * 16 + l15;
        float br = Brb[n], bg = Bgb[n];
        #pragma unroll
        for (int mf = 0; mf < 4; mf++) {
            long rowb = m0 + mf * 16 + g * 4;
            #pragma unroll
            for (int r = 0; r < 4; r++) {
                float pr = accR[mf][nt][r] + br;
                float pg = accG[mf][nt][r] + bg;
                float x = fminf(fmaxf(pr, -30.f), 30.f);
                float e2 = __expf(2.f * x);
                float rr = (e2 - 1.f) / (e2 + 1.f);
                float gv = 1.0f / (1.0f + __expf(-pg));
                float cv = h2f(c16g[(rowb + r) * DDD + n]);
                outg[(rowb + r) * DDD + n] = gv * rr + (1.f - gv) * cv;
            }
        }
    }
}

extern "C" void kernel_launch(void* const* d_in, const int* in_sizes, int n_in,
                              void* d_out, int out_size, void* d_ws, size_t ws_size,
                              hipStream_t stream) {
    const float* c  = (const float*)d_in[0];
    const float* q  = (const float*)d_in[1];
    const float* Wr = (const float*)d_in[2];
    const float* Br = (const float*)d_in[3];
    const float* Wg = (const float*)d_in[4];
    const float* Bg = (const float*)d_in[5];
    const void* cmask = d_in[6];
    const void* qmask = d_in[7];

    char* ws = (char*)d_ws;
    uint16_t* qS    = (uint16_t*)(ws + 0);          //  4,194,304 B
    uint16_t* qTS   = (uint16_t*)(ws + 4194304);    //  4,194,304 B
    uint16_t* qa16  = (uint16_t*)(ws + 8388608);    // 33,554,432 B
    uint16_t* c16   = (uint16_t*)(ws + 41943040);   // 33,554,432 B
    uint16_t* WP3   = (uint16_t*)(ws + 75497472);   //    786,432 B
    uint8_t*  cm8   = (uint8_t*)(ws + 77594624);    //     65,536 B
    uint8_t*  qm8   = (uint8_t*)(ws + 77660160);    //      8,192 B
    (void)in_sizes; (void)n_in; (void)out_size; (void)ws_size;

    k_prep<<<dim3(816), dim3(256), 0, stream>>>(cmask, qmask, q, Wr, Wg,
                                                cm8, qm8, qS, qTS, WP3);
    k_attn<<<dim3(JXX / 128, NB), dim3(256), 0, stream>>>(c, qS, qTS, cm8, qm8, qa16, c16);
    k_sfu<<<dim3((NB * JXX) / 64), dim3(256), 0, stream>>>(
        c16, qa16, WP3, Br, Bg, (float*)d_out);
}